// Round 1
// baseline (1243.869 us; speedup 1.0000x reference)
//
#include <hip/hip_runtime.h>
#include <math.h>

#define NROWS 262144
#define NCOLS 128
#define NPART 1024
#define MAXTIES 256

struct Accum {
  double kl_part[NPART];
  double tls_part[NPART];
  double clean_part[NPART];
  double corr_part[NPART];
  double cnt_part[NPART];
  unsigned int num_remember;
  unsigned int binB;
  unsigned int rem1;
  unsigned int T;
  unsigned int needed;
  unsigned int tie_cnt;
  unsigned int tie_idx[MAXTIES];
};

// ---------- K1: per-row stats (one 64-lane wave per row, 2 cols/lane) ----------
__device__ __forceinline__ void head_stats(float2 v, int lane,
                                           float& m_out, int& am_out, float& z_out,
                                           float& ex, float& ey) {
  float lm = v.x; int li = 2 * lane;
  if (v.y > lm) { lm = v.y; li = 2 * lane + 1; }   // strict >: first-occurrence argmax
#pragma unroll
  for (int msk = 1; msk < 64; msk <<= 1) {
    float om = __shfl_xor(lm, msk, 64);
    int   oi = __shfl_xor(li, msk, 64);
    if (om > lm || (om == lm && oi < li)) { lm = om; li = oi; }
  }
  ex = __expf(v.x - lm); ey = __expf(v.y - lm);
  float s = ex + ey;
#pragma unroll
  for (int msk = 1; msk < 64; msk <<= 1) s += __shfl_xor(s, msk, 64);
  m_out = lm; am_out = li; z_out = s;
}

__global__ __launch_bounds__(256) void k_rows(
    const float* __restrict__ y1, const float* __restrict__ y2,
    const int* __restrict__ tgt,
    float* __restrict__ tl, float* __restrict__ corr, unsigned char* __restrict__ mask,
    unsigned int* __restrict__ hist1, Accum* __restrict__ acc) {
  int wid = threadIdx.x >> 6, lane = threadIdx.x & 63;
  int row = blockIdx.x * 4 + wid;

  const float2* r1 = reinterpret_cast<const float2*>(y1) + (size_t)row * 64 + lane;
  const float2* r2 = reinterpret_cast<const float2*>(y2) + (size_t)row * 64 + lane;
  float2 a = *r1;
  float2 b = *r2;

  float m1, z1, e1x, e1y; int am1;
  head_stats(a, lane, m1, am1, z1, e1x, e1y);
  float m2, z2, e2x, e2y; int am2;
  head_stats(b, lane, m2, am2, z2, e2x, e2y);

  float logZ1 = m1 + __logf(z1);
  float logZ2 = m2 + __logf(z2);
  float rz1 = 1.0f / z1;   // == conf1 = max softmax prob of head1
  float rz2 = 1.0f / z2;

  // gather logits at target class
  int t = tgt[row];
  int sl = t >> 1, odd = t & 1;
  float g1x = __shfl(a.x, sl, 64), g1y = __shfl(a.y, sl, 64);
  float g2x = __shfl(b.x, sl, 64), g2y = __shfl(b.y, sl, 64);
  float y1t = odd ? g1y : g1x;
  float y2t = odd ? g2y : g2x;
  float total = (logZ1 - y1t) + (logZ2 - y2t);   // >= 0

  // symmetric KL row term: sum_j (p1-p2)*(logp1-logp2)
  float lp1x = a.x - logZ1, lp1y = a.y - logZ1;
  float lp2x = b.x - logZ2, lp2y = b.y - logZ2;
  float p1x = e1x * rz1, p1y = e1y * rz1;
  float p2x = e2x * rz2, p2y = e2y * rz2;
  float kl = (p1x - p2x) * (lp1x - lp2x) + (p1y - p2y) * (lp1y - lp2y);
#pragma unroll
  for (int msk = 1; msk < 64; msk <<= 1) kl += __shfl_xor(kl, msk, 64);

  // correction-term ingredients (used only if row lands in noisy set)
  int pl = am1;                     // pseudo-label = argmax of head1
  int sl2 = pl >> 1;
  float h2x = __shfl(b.x, sl2, 64), h2y = __shfl(b.y, sl2, 64);
  float y2pl = (pl & 1) ? h2y : h2x;
  float ce1 = logZ1 - m1;           // y1[pl] == m1
  float ce2 = logZ2 - y2pl;
  float prod = rz1 * rz2;
  int ok = (am1 == am2) && (prod > 0.5f);
  float corrv = sqrtf(prod) * (ce1 + ce2);

  if (lane == 0) {
    tl[row] = total;
    corr[row] = corrv;
    mask[row] = (unsigned char)ok;
    atomicAdd(&hist1[__float_as_uint(total) >> 16], 1u);
  }

  __shared__ double sdk[4], sdt[4];
  if (lane == 0) { sdk[wid] = (double)kl; sdt[wid] = (double)total; }
  __syncthreads();
  if (threadIdx.x == 0) {
    int slot = blockIdx.x & (NPART - 1);
    atomicAdd(&acc->kl_part[slot],  sdk[0] + sdk[1] + sdk[2] + sdk[3]);
    atomicAdd(&acc->tls_part[slot], sdt[0] + sdt[1] + sdt[2] + sdt[3]);
  }
}

// ---------- K2/K2d: find k-th smallest key bin within a 65536-bin histogram ----------
__global__ __launch_bounds__(256) void k_scan(const unsigned int* __restrict__ hist,
                                              Accum* __restrict__ acc,
                                              const int* __restrict__ epoch_p, int mode) {
  __shared__ unsigned int psum[256];
  __shared__ unsigned int bins[256];
  __shared__ unsigned int chunk_s, base_s, k_s;
  int t = threadIdx.x;

  unsigned int local = 0;
  const uint4* hp = reinterpret_cast<const uint4*>(hist + t * 256);
#pragma unroll 4
  for (int i = 0; i < 64; i++) { uint4 h = hp[i]; local += h.x + h.y + h.z + h.w; }
  psum[t] = local;
  __syncthreads();

  if (t == 0) {
    unsigned int k;
    if (mode == 0) {
      int ep = epoch_p[0];
      double fr = (0.5 / 100.0) * (double)ep; if (fr > 0.5) fr = 0.5;
      double rr = 1.0 - fr;                   if (rr < 0.5) rr = 0.5;
      unsigned int nr = (unsigned int)(rr * (double)NROWS);
      acc->num_remember = nr;
      k = nr;
    } else {
      k = acc->rem1;
    }
    unsigned int cum = 0, chunk = 255;
    for (int i = 0; i < 256; i++) {
      unsigned int h = psum[i];
      if (cum + h >= k) { chunk = i; break; }
      cum += h;
    }
    chunk_s = chunk; base_s = cum; k_s = k;
  }
  __syncthreads();
  bins[t] = hist[chunk_s * 256 + t];
  __syncthreads();
  if (t == 0) {
    unsigned int k = k_s, c = base_s, bin = chunk_s * 256 + 255, rem = 1;
    for (int i = 0; i < 256; i++) {
      unsigned int h = bins[i];
      if (c + h >= k) { bin = chunk_s * 256 + i; rem = k - c; break; }
      c += h;
    }
    if (mode == 0) { acc->binB = bin; acc->rem1 = rem; }
    else           { acc->T = (acc->binB << 16) | bin; acc->needed = rem; }
  }
}

// ---------- K2c: refine histogram over low 16 bits within bin B ----------
__global__ __launch_bounds__(256) void k_refine(const float* __restrict__ tl,
                                                unsigned int* __restrict__ hist2,
                                                const Accum* __restrict__ acc) {
  int i = blockIdx.x * 256 + threadIdx.x;
  unsigned int B = acc->binB;
  unsigned int key = __float_as_uint(tl[i]);
  if ((key >> 16) == B) atomicAdd(&hist2[key & 0xFFFFu], 1u);
}

// ---------- block reduction helper ----------
__device__ __forceinline__ double block_sum_d(double v, double* s) {
#pragma unroll
  for (int msk = 1; msk < 64; msk <<= 1) v += __shfl_xor(v, msk, 64);
  int wid = threadIdx.x >> 6, lane = threadIdx.x & 63;
  __syncthreads();
  if (lane == 0) s[wid] = v;
  __syncthreads();
  return s[0] + s[1] + s[2] + s[3];
}

// ---------- K3: partition rows by threshold key ----------
__global__ __launch_bounds__(256) void k_partition(const float* __restrict__ tl,
                                                   const float* __restrict__ corr,
                                                   const unsigned char* __restrict__ mask,
                                                   Accum* __restrict__ acc) {
  __shared__ double sred[4];
  int i = blockIdx.x * 256 + threadIdx.x;
  unsigned int T = acc->T;
  unsigned int key = __float_as_uint(tl[i]);
  double cl = 0.0, co = 0.0, cn = 0.0;
  if (key < T) {
    cl = (double)tl[i];
  } else if (key == T) {
    unsigned int p = atomicAdd(&acc->tie_cnt, 1u);
    if (p < MAXTIES) acc->tie_idx[p] = (unsigned int)i;
  } else {
    if (mask[i]) { co = (double)corr[i]; cn = 1.0; }
  }
  double scl = block_sum_d(cl, sred);
  double sco = block_sum_d(co, sred);
  double scn = block_sum_d(cn, sred);
  if (threadIdx.x == 0) {
    acc->clean_part[blockIdx.x] = scl;
    acc->corr_part[blockIdx.x]  = sco;
    acc->cnt_part[blockIdx.x]   = scn;
  }
}

// ---------- K4: finalize ----------
__global__ __launch_bounds__(256) void k_final(const float* __restrict__ corr,
                                               const unsigned char* __restrict__ mask,
                                               Accum* __restrict__ acc,
                                               const int* __restrict__ epoch_p,
                                               float* __restrict__ out) {
  __shared__ double sred[4];
  int t = threadIdx.x;
  double kl = 0, tls = 0, cl = 0, co = 0, cn = 0;
  for (int i = t; i < NPART; i += 256) {
    kl  += acc->kl_part[i];
    tls += acc->tls_part[i];
    cl  += acc->clean_part[i];
    co  += acc->corr_part[i];
    cn  += acc->cnt_part[i];
  }
  kl  = block_sum_d(kl,  sred);
  tls = block_sum_d(tls, sred);
  cl  = block_sum_d(cl,  sred);
  co  = block_sum_d(co,  sred);
  cn  = block_sum_d(cn,  sred);

  if (t == 0) {
    int ep = epoch_p[0];
    if (ep == 0) { out[0] = (float)(tls / (double)NROWS); return; }

    unsigned int needed = acc->needed;
    unsigned int m = acc->tie_cnt; if (m > MAXTIES) m = MAXTIES;
    float Tval = __uint_as_float(acc->T);
    cl += (double)Tval * (double)needed;     // ties going to the clean set (equal values)
    if (m > needed) {
      // stable argsort breaks ties by row index: sort recorded tie indices
      for (int a2 = 1; a2 < (int)m; a2++) {
        unsigned int v = acc->tie_idx[a2];
        int b2 = a2 - 1;
        while (b2 >= 0 && acc->tie_idx[b2] > v) { acc->tie_idx[b2 + 1] = acc->tie_idx[b2]; b2--; }
        acc->tie_idx[b2 + 1] = v;
      }
      for (unsigned int j = needed; j < m; j++) {
        unsigned int idx = acc->tie_idx[j];
        if (mask[idx]) { co += (double)corr[idx]; cn += 1.0; }
      }
    }
    double clean_loss = cl / (double)acc->num_remember;
    double corr_mean = (cn > 0.5) ? (co / cn) : 0.0;
    double kl_mean = kl / (double)NROWS;
    out[0] = (float)(clean_loss + corr_mean + 0.1 * kl_mean);
  }
}

extern "C" void kernel_launch(void* const* d_in, const int* in_sizes, int n_in,
                              void* d_out, int out_size, void* d_ws, size_t ws_size,
                              hipStream_t stream) {
  const float* y1 = (const float*)d_in[0];
  const float* y2 = (const float*)d_in[1];
  const int* tgt = (const int*)d_in[2];
  const int* epoch = (const int*)d_in[3];
  float* out = (float*)d_out;

  float* tl = (float*)d_ws;                                   // N floats
  float* corr = tl + NROWS;                                   // N floats
  unsigned char* mask = (unsigned char*)(corr + NROWS);       // N bytes
  unsigned int* hist1 = (unsigned int*)(mask + NROWS);        // 65536
  unsigned int* hist2 = hist1 + 65536;                        // 65536
  Accum* acc = (Accum*)(hist2 + 65536);

  hipMemsetAsync(hist1, 0, 2 * 65536 * sizeof(unsigned int) + sizeof(Accum), stream);

  k_rows<<<NROWS / 4, 256, 0, stream>>>(y1, y2, tgt, tl, corr, mask, hist1, acc);
  k_scan<<<1, 256, 0, stream>>>(hist1, acc, epoch, 0);
  k_refine<<<NROWS / 256, 256, 0, stream>>>(tl, hist2, acc);
  k_scan<<<1, 256, 0, stream>>>(hist2, acc, epoch, 1);
  k_partition<<<NROWS / 256, 256, 0, stream>>>(tl, corr, mask, acc);
  k_final<<<1, 256, 0, stream>>>(corr, mask, acc, epoch, out);
}

// Round 2
// 362.506 us; speedup vs baseline: 3.4313x; 3.4313x over previous
//
#include <hip/hip_runtime.h>
#include <math.h>

#define NROWS 262144
#define NPART 1024
#define MAXTIES 256
#define H1BINS 4096
#define H2BINS 4096
#define H3BINS 256
typedef unsigned int uint;

struct Accum {
  double kl_part[NPART];
  double tls_part[NPART];
  double clean_part[NPART];
  double corr_part[NPART];
  double cnt_part[NPART];
  uint tie_cnt;
  uint tie_idx[MAXTIES];
};

// ---------------- K1: per-row stats. 16 lanes per row, 4 rows per wave. ----------------
// Wave reads 2KB contiguous from each of y1,y2. No histogram here (L2 atomic serialization
// on hot lines was the 1000us elephant in round 1).
__global__ __launch_bounds__(256) void k_rows(
    const float* __restrict__ y1, const float* __restrict__ y2,
    const int* __restrict__ tgt,
    float* __restrict__ tl, float* __restrict__ corr, unsigned char* __restrict__ mask,
    Accum* __restrict__ acc) {
  const int tid = threadIdx.x;
  const int w = tid >> 6, l = tid & 63;
  const int wavebase = blockIdx.x * 16 + w * 4;   // first of this wave's 4 rows
  const int row = wavebase + (l >> 4);
  const int seg = l & 15;                          // 16-lane group position
  const int base = seg * 8;                        // first col this lane owns
  const int gs = l & 48;                           // group start lane

  const float4* p1 = reinterpret_cast<const float4*>(y1 + (size_t)wavebase * 128) + 2 * l;
  const float4* p2 = reinterpret_cast<const float4*>(y2 + (size_t)wavebase * 128) + 2 * l;
  float4 a0 = p1[0], a1 = p1[1];
  float4 b0 = p2[0], b1 = p2[1];
  int t = tgt[row];

  float av[8] = {a0.x, a0.y, a0.z, a0.w, a1.x, a1.y, a1.z, a1.w};
  float bv[8] = {b0.x, b0.y, b0.z, b0.w, b1.x, b1.y, b1.z, b1.w};

  // ---- head 1: max/argmax (first-occurrence), Z ----
  float m1 = av[0]; int i1 = 0;
#pragma unroll
  for (int j = 1; j < 8; j++) if (av[j] > m1) { m1 = av[j]; i1 = j; }
  i1 += base;
#pragma unroll
  for (int msk = 1; msk < 16; msk <<= 1) {
    float om = __shfl_xor(m1, msk, 64);
    int oi = __shfl_xor(i1, msk, 64);
    if (om > m1 || (om == m1 && oi < i1)) { m1 = om; i1 = oi; }
  }
  float e1[8];
#pragma unroll
  for (int j = 0; j < 8; j++) e1[j] = __expf(av[j] - m1);
  float z1 = 0.f;
#pragma unroll
  for (int j = 0; j < 8; j++) z1 += e1[j];
#pragma unroll
  for (int msk = 1; msk < 16; msk <<= 1) z1 += __shfl_xor(z1, msk, 64);
  float logZ1 = m1 + __logf(z1);
  float rz1 = 1.0f / z1;       // == conf1 (max softmax prob)

  // ---- head 2 ----
  float m2 = bv[0]; int i2 = 0;
#pragma unroll
  for (int j = 1; j < 8; j++) if (bv[j] > m2) { m2 = bv[j]; i2 = j; }
  i2 += base;
#pragma unroll
  for (int msk = 1; msk < 16; msk <<= 1) {
    float om = __shfl_xor(m2, msk, 64);
    int oi = __shfl_xor(i2, msk, 64);
    if (om > m2 || (om == m2 && oi < i2)) { m2 = om; i2 = oi; }
  }
  float e2[8];
#pragma unroll
  for (int j = 0; j < 8; j++) e2[j] = __expf(bv[j] - m2);
  float z2 = 0.f;
#pragma unroll
  for (int j = 0; j < 8; j++) z2 += e2[j];
#pragma unroll
  for (int msk = 1; msk < 16; msk <<= 1) z2 += __shfl_xor(z2, msk, 64);
  float logZ2 = m2 + __logf(z2);
  float rz2 = 1.0f / z2;

  // ---- symmetric KL row term: sum_j (p1-p2)*(logp1-logp2) ----
  float kl = 0.f;
#pragma unroll
  for (int j = 0; j < 8; j++)
    kl += (e1[j] * rz1 - e2[j] * rz2) * ((av[j] - logZ1) - (bv[j] - logZ2));
#pragma unroll
  for (int msk = 1; msk < 16; msk <<= 1) kl += __shfl_xor(kl, msk, 64);

  // ---- gathers: logits at target col t, and y2 at pseudo-label i1 ----
  float pa = 0.f, pb = 0.f, pc = 0.f;
#pragma unroll
  for (int j = 0; j < 8; j++) {
    pa = (t == base + j) ? av[j] : pa;
    pb = (t == base + j) ? bv[j] : pb;
    pc = (i1 == base + j) ? bv[j] : pc;
  }
  float y1t = __shfl(pa, gs + (t >> 3), 64);
  float y2t = __shfl(pb, gs + (t >> 3), 64);
  float y2pl = __shfl(pc, gs + (i1 >> 3), 64);

  float total = (logZ1 - y1t) + (logZ2 - y2t);   // >= 0
  float prod = rz1 * rz2;
  int ok = (i1 == i2) && (prod > 0.5f);
  float corrv = sqrtf(prod) * ((logZ1 - m1) + (logZ2 - y2pl));

  __shared__ float skl[16], stt[16];
  if (seg == 0) {
    tl[row] = total;
    corr[row] = corrv;
    mask[row] = (unsigned char)ok;
    skl[tid >> 4] = kl;
    stt[tid >> 4] = total;
  }
  __syncthreads();
  if (tid == 0) {
    double sk = 0.0, st = 0.0;
#pragma unroll
    for (int i = 0; i < 16; i++) { sk += (double)skl[i]; st += (double)stt[i]; }
    int slot = blockIdx.x & (NPART - 1);
    atomicAdd(&acc->kl_part[slot], sk);
    atomicAdd(&acc->tls_part[slot], st);
  }
}

// ---------------- K2: level-1 histogram (top 12 bits), LDS-privatized ----------------
__global__ __launch_bounds__(1024) void k_hist1(const float* __restrict__ tl,
                                                uint* __restrict__ hist1) {
  __shared__ uint h[H1BINS];
  int tid = threadIdx.x;
  for (int j = tid; j < H1BINS; j += 1024) h[j] = 0;
  __syncthreads();
  int i0 = blockIdx.x * 2048 + tid;          // 128 blocks x 2048 rows
  uint k0 = __float_as_uint(tl[i0]) >> 20;
  uint k1 = __float_as_uint(tl[i0 + 1024]) >> 20;
  atomicAdd(&h[k0], 1u);
  atomicAdd(&h[k1], 1u);
  __syncthreads();
  for (int j = tid; j < H1BINS; j += 1024) {
    uint v = h[j];
    if (v) atomicAdd(&hist1[j], v);          // <=128 atomics per address, staggered
  }
}

// ---------------- shared helpers ----------------
__device__ __forceinline__ uint calc_nr(int ep) {
  double fr = 0.005 * (double)ep; if (fr > 0.5) fr = 0.5;
  double rr = 1.0 - fr;           if (rr < 0.5) rr = 0.5;
  return (uint)(rr * (double)NROWS);
}

// Find smallest bin with cum+h >= k. All threads of the block see the result.
__device__ void scan_hist(const uint* __restrict__ hist, int L, uint k,
                          uint* psum, uint* out_bin, uint* out_rem) {
  int t = threadIdx.x;
  int per = L >> 8;                    // 16 or 1
  uint local = 0;
  for (int j = 0; j < per; j++) local += hist[t * per + j];
  psum[t] = local;
  __syncthreads();
  if (t == 0) {
    uint cum = 0; int chunk = 255;
    for (int i = 0; i < 256; i++) { uint hh = psum[i]; if (cum + hh >= k) { chunk = i; break; } cum += hh; }
    uint bin = (uint)(chunk * per + per - 1), rem = 1, c = cum;
    for (int j = 0; j < per; j++) {
      uint hh = hist[chunk * per + j];
      if (c + hh >= k) { bin = (uint)(chunk * per + j); rem = k - c; break; }
      c += hh;
    }
    *out_bin = bin; *out_rem = rem;
  }
  __syncthreads();
}

__device__ __forceinline__ double block_sum_d(double v, double* s) {
#pragma unroll
  for (int msk = 1; msk < 64; msk <<= 1) v += __shfl_xor(v, msk, 64);
  int wid = threadIdx.x >> 6, lane = threadIdx.x & 63;
  __syncthreads();
  if (lane == 0) s[wid] = v;
  __syncthreads();
  return s[0] + s[1] + s[2] + s[3];
}

// ---------------- K3: level-2 histogram (bits 19:8) gated on B1 ----------------
__global__ __launch_bounds__(256) void k_hist2(const float* __restrict__ tl,
                                               const uint* __restrict__ hist1,
                                               uint* __restrict__ hist2,
                                               const int* __restrict__ ep) {
  __shared__ uint psum[256]; __shared__ uint sb, sr;
  scan_hist(hist1, H1BINS, calc_nr(ep[0]), psum, &sb, &sr);
  int i = blockIdx.x * 256 + threadIdx.x;
  uint key = __float_as_uint(tl[i]);
  if ((key >> 20) == sb) atomicAdd(&hist2[(key >> 8) & 0xFFFu], 1u);
}

// ---------------- K4: level-3 histogram (bits 7:0) gated on B1,B2 ----------------
__global__ __launch_bounds__(256) void k_hist3(const float* __restrict__ tl,
                                               const uint* __restrict__ hist1,
                                               const uint* __restrict__ hist2,
                                               uint* __restrict__ hist3,
                                               const int* __restrict__ ep) {
  __shared__ uint psum[256]; __shared__ uint sb, sr;
  scan_hist(hist1, H1BINS, calc_nr(ep[0]), psum, &sb, &sr);
  uint B1 = sb, r1 = sr;
  scan_hist(hist2, H2BINS, r1, psum, &sb, &sr);
  uint pref = (B1 << 12) | sb;
  int i = blockIdx.x * 256 + threadIdx.x;
  uint key = __float_as_uint(tl[i]);
  if ((key >> 8) == pref) atomicAdd(&hist3[key & 0xFFu], 1u);
}

// ---------------- K5: partition by threshold key T ----------------
__global__ __launch_bounds__(256) void k_partition(const float* __restrict__ tl,
                                                   const float* __restrict__ corr,
                                                   const unsigned char* __restrict__ mask,
                                                   const uint* __restrict__ hist1,
                                                   const uint* __restrict__ hist2,
                                                   const uint* __restrict__ hist3,
                                                   const int* __restrict__ ep,
                                                   Accum* __restrict__ acc) {
  __shared__ uint psum[256]; __shared__ uint sb, sr;
  __shared__ double sred[4];
  scan_hist(hist1, H1BINS, calc_nr(ep[0]), psum, &sb, &sr);
  uint B1 = sb, r1 = sr;
  scan_hist(hist2, H2BINS, r1, psum, &sb, &sr);
  uint B2 = sb, r2 = sr;
  scan_hist(hist3, H3BINS, r2, psum, &sb, &sr);
  uint T = (B1 << 20) | (B2 << 8) | sb;

  int i = blockIdx.x * 256 + threadIdx.x;
  uint key = __float_as_uint(tl[i]);
  double cl = 0.0, co = 0.0, cn = 0.0;
  if (key < T) {
    cl = (double)tl[i];
  } else if (key == T) {
    uint p = atomicAdd(&acc->tie_cnt, 1u);
    if (p < MAXTIES) acc->tie_idx[p] = (uint)i;
  } else {
    if (mask[i]) { co = (double)corr[i]; cn = 1.0; }
  }
  double scl = block_sum_d(cl, sred);
  double sco = block_sum_d(co, sred);
  double scn = block_sum_d(cn, sred);
  if (threadIdx.x == 0) {
    acc->clean_part[blockIdx.x] = scl;
    acc->corr_part[blockIdx.x]  = sco;
    acc->cnt_part[blockIdx.x]   = scn;
  }
}

// ---------------- K6: finalize ----------------
__global__ __launch_bounds__(256) void k_final(const float* __restrict__ corr,
                                               const unsigned char* __restrict__ mask,
                                               const uint* __restrict__ hist1,
                                               const uint* __restrict__ hist2,
                                               const uint* __restrict__ hist3,
                                               Accum* __restrict__ acc,
                                               const int* __restrict__ ep,
                                               float* __restrict__ out) {
  __shared__ uint psum[256]; __shared__ uint sb, sr;
  __shared__ double sred[4];
  int t = threadIdx.x;
  uint nr = calc_nr(ep[0]);
  scan_hist(hist1, H1BINS, nr, psum, &sb, &sr);
  uint B1 = sb, r1 = sr;
  scan_hist(hist2, H2BINS, r1, psum, &sb, &sr);
  uint B2 = sb, r2 = sr;
  scan_hist(hist3, H3BINS, r2, psum, &sb, &sr);
  uint T = (B1 << 20) | (B2 << 8) | sb;
  uint needed = sr;

  double kl = 0, tls = 0, cl = 0, co = 0, cn = 0;
  for (int i = t; i < NPART; i += 256) {
    kl  += acc->kl_part[i];
    tls += acc->tls_part[i];
    cl  += acc->clean_part[i];
    co  += acc->corr_part[i];
    cn  += acc->cnt_part[i];
  }
  kl  = block_sum_d(kl,  sred);
  tls = block_sum_d(tls, sred);
  cl  = block_sum_d(cl,  sred);
  co  = block_sum_d(co,  sred);
  cn  = block_sum_d(cn,  sred);

  if (t == 0) {
    int e = ep[0];
    if (e == 0) { out[0] = (float)(tls / (double)NROWS); return; }

    uint m = acc->tie_cnt; if (m > MAXTIES) m = MAXTIES;
    float Tval = __uint_as_float(T);
    cl += (double)Tval * (double)needed;     // ties landing in clean set (identical value)
    if (m > needed) {
      // stable argsort tie-break by row index: sort recorded tie indices
      for (int a2 = 1; a2 < (int)m; a2++) {
        uint v = acc->tie_idx[a2];
        int b2 = a2 - 1;
        while (b2 >= 0 && acc->tie_idx[b2] > v) { acc->tie_idx[b2 + 1] = acc->tie_idx[b2]; b2--; }
        acc->tie_idx[b2 + 1] = v;
      }
      for (uint j = needed; j < m; j++) {
        uint idx = acc->tie_idx[j];
        if (mask[idx]) { co += (double)corr[idx]; cn += 1.0; }
      }
    }
    double clean_loss = cl / (double)nr;
    double corr_mean = (cn > 0.5) ? (co / cn) : 0.0;
    double kl_mean = kl / (double)NROWS;
    out[0] = (float)(clean_loss + corr_mean + 0.1 * kl_mean);
  }
}

extern "C" void kernel_launch(void* const* d_in, const int* in_sizes, int n_in,
                              void* d_out, int out_size, void* d_ws, size_t ws_size,
                              hipStream_t stream) {
  const float* y1 = (const float*)d_in[0];
  const float* y2 = (const float*)d_in[1];
  const int* tgt = (const int*)d_in[2];
  const int* epoch = (const int*)d_in[3];
  float* out = (float*)d_out;

  float* tl = (float*)d_ws;                                   // N floats
  float* corrv = tl + NROWS;                                  // N floats
  unsigned char* mask = (unsigned char*)(corrv + NROWS);      // N bytes
  uint* hist1 = (uint*)(mask + NROWS);                        // 4096
  uint* hist2 = hist1 + H1BINS;                               // 4096
  uint* hist3 = hist2 + H2BINS;                               // 256
  Accum* acc = (Accum*)(hist3 + H3BINS);

  size_t zbytes = (size_t)(H1BINS + H2BINS + H3BINS) * 4 + sizeof(Accum);
  hipMemsetAsync(hist1, 0, zbytes, stream);

  k_rows<<<NROWS / 16, 256, 0, stream>>>(y1, y2, tgt, tl, corrv, mask, acc);
  k_hist1<<<128, 1024, 0, stream>>>(tl, hist1);
  k_hist2<<<NROWS / 256, 256, 0, stream>>>(tl, hist1, hist2, epoch);
  k_hist3<<<NROWS / 256, 256, 0, stream>>>(tl, hist1, hist2, hist3, epoch);
  k_partition<<<NROWS / 256, 256, 0, stream>>>(tl, corrv, mask, hist1, hist2, hist3, epoch, acc);
  k_final<<<1, 256, 0, stream>>>(corrv, mask, hist1, hist2, hist3, acc, epoch, out);
}

// Round 3
// 307.979 us; speedup vs baseline: 4.0388x; 1.1770x over previous
//
#include <hip/hip_runtime.h>
#include <math.h>

#define NROWS 262144
#define NPART 1024
#define MAXTIES 256
#define H1BINS 4096
#define H2BINS 4096
#define H3BINS 256
typedef unsigned int uint;

struct Accum {
  double kl_part[NPART];
  double tls_part[NPART];
  double clean_part[NPART];
  double corr_part[NPART];
  double cnt_part[NPART];
  uint tie_cnt;
  uint tie_idx[MAXTIES];
};

// ============ parallel bin-select helpers (replaces thread-0 serial scans) ============
// 256 threads each hold count h; find first t with inclusive-prefix >= k.
// Unique winner: incl >= k && excl < k (h==0 can't win). Results in binrem[0..1].
__device__ __forceinline__ void select256(uint h, uint k, uint* wsum, uint* binrem) {
  int t = threadIdx.x, l = t & 63, w = t >> 6;
  uint incl = h;
#pragma unroll
  for (int d = 1; d < 64; d <<= 1) {
    uint o = __shfl_up(incl, d, 64);
    incl += (l >= d) ? o : 0u;
  }
  if (l == 63) wsum[w] = incl;
  __syncthreads();
  uint off = 0;
#pragma unroll
  for (int i = 0; i < 3; i++) off += (i < w) ? wsum[i] : 0u;
  incl += off;
  uint excl = incl - h;
  if (incl >= k && excl < k) { binrem[0] = (uint)t; binrem[1] = k - excl; }
  __syncthreads();
}

// Find smallest bin with cumsum >= k in an L-bin histogram (L = 4096 or 256).
__device__ __forceinline__ void hist_select(const uint* __restrict__ hist, int L, uint k,
                                            uint* wsum, uint* binrem,
                                            uint* out_bin, uint* out_rem) {
  int t = threadIdx.x;
  if (L == 4096) {
    const uint4* hp = reinterpret_cast<const uint4*>(hist + t * 16);
    uint4 v0 = hp[0], v1 = hp[1], v2 = hp[2], v3 = hp[3];
    uint h = v0.x + v0.y + v0.z + v0.w + v1.x + v1.y + v1.z + v1.w
           + v2.x + v2.y + v2.z + v2.w + v3.x + v3.y + v3.z + v3.w;
    select256(h, k, wsum, binrem);
    uint chunk = binrem[0], rem1 = binrem[1];
    __syncthreads();
    uint h2 = (t < 16) ? hist[chunk * 16 + t] : 0u;
    select256(h2, rem1, wsum, binrem);
    *out_bin = chunk * 16 + binrem[0];
    *out_rem = binrem[1];
    __syncthreads();
  } else {
    uint h = hist[t];
    select256(h, k, wsum, binrem);
    *out_bin = binrem[0];
    *out_rem = binrem[1];
    __syncthreads();
  }
}

__device__ __forceinline__ uint calc_nr(int ep) {
  double fr = 0.005 * (double)ep; if (fr > 0.5) fr = 0.5;
  double rr = 1.0 - fr;           if (rr < 0.5) rr = 0.5;
  return (uint)(rr * (double)NROWS);
}

__device__ __forceinline__ double block_sum_d(double v, double* s) {
#pragma unroll
  for (int msk = 1; msk < 64; msk <<= 1) v += __shfl_xor(v, msk, 64);
  int wid = threadIdx.x >> 6, lane = threadIdx.x & 63;
  __syncthreads();
  if (lane == 0) s[wid] = v;
  __syncthreads();
  return s[0] + s[1] + s[2] + s[3];
}

// ============ K1: per-row stats, 16 lanes/row, 8 rows/wave (2 independent chains) ============
__device__ __forceinline__ void process_group(
    const float av[8], const float bv[8], int t, int row, int seg, int base,
    const float* __restrict__ y1, const float* __restrict__ y2,
    float* __restrict__ tl, float* __restrict__ corr, unsigned char* __restrict__ mask,
    float* skl, float* stt, int slot) {
  // head1 max/argmax (first occurrence)
  float m1 = av[0]; int i1 = 0;
#pragma unroll
  for (int j = 1; j < 8; j++) { if (av[j] > m1) { m1 = av[j]; i1 = j; } }
  i1 += base;
#pragma unroll
  for (int msk = 1; msk < 16; msk <<= 1) {
    float om = __shfl_xor(m1, msk, 64);
    int oi = __shfl_xor(i1, msk, 64);
    if (om > m1 || (om == m1 && oi < i1)) { m1 = om; i1 = oi; }
  }
  float m2 = bv[0]; int i2 = 0;
#pragma unroll
  for (int j = 1; j < 8; j++) { if (bv[j] > m2) { m2 = bv[j]; i2 = j; } }
  i2 += base;
#pragma unroll
  for (int msk = 1; msk < 16; msk <<= 1) {
    float om = __shfl_xor(m2, msk, 64);
    int oi = __shfl_xor(i2, msk, 64);
    if (om > m2 || (om == m2 && oi < i2)) { m2 = om; i2 = oi; }
  }
  float e1[8], e2[8];
  float z1 = 0.f, z2 = 0.f;
#pragma unroll
  for (int j = 0; j < 8; j++) { e1[j] = __expf(av[j] - m1); z1 += e1[j]; }
#pragma unroll
  for (int j = 0; j < 8; j++) { e2[j] = __expf(bv[j] - m2); z2 += e2[j]; }
#pragma unroll
  for (int msk = 1; msk < 16; msk <<= 1) z1 += __shfl_xor(z1, msk, 64);
#pragma unroll
  for (int msk = 1; msk < 16; msk <<= 1) z2 += __shfl_xor(z2, msk, 64);
  float logZ1 = m1 + __logf(z1), logZ2 = m2 + __logf(z2);
  float rz1 = 1.f / z1, rz2 = 1.f / z2;
  float dZ = logZ1 - logZ2;
  float kl = 0.f;
#pragma unroll
  for (int j = 0; j < 8; j++)
    kl += (e1[j] * rz1 - e2[j] * rz2) * ((av[j] - bv[j]) - dZ);
#pragma unroll
  for (int msk = 1; msk < 16; msk <<= 1) kl += __shfl_xor(kl, msk, 64);

  if (seg == 0) {
    // direct cache-hot loads replace shuffle-gather loops (the lines are L1/L2 resident)
    const float* r1p = y1 + (size_t)row * 128;
    const float* r2p = y2 + (size_t)row * 128;
    float y1t = r1p[t], y2t = r2p[t], y2pl = r2p[i1];
    float total = (logZ1 - y1t) + (logZ2 - y2t);   // >= 0
    float prod = rz1 * rz2;                        // conf1*conf2
    float corrv = sqrtf(prod) * ((logZ1 - m1) + (logZ2 - y2pl));
    tl[row] = total;
    corr[row] = corrv;
    mask[row] = (unsigned char)((i1 == i2) && (prod > 0.5f));
    skl[slot] = kl;
    stt[slot] = total;
  }
}

__global__ __launch_bounds__(256) void k_rows(
    const float* __restrict__ y1, const float* __restrict__ y2,
    const int* __restrict__ tgt,
    float* __restrict__ tl, float* __restrict__ corr, unsigned char* __restrict__ mask,
    Accum* __restrict__ acc) {
  const int tid = threadIdx.x;
  const int w = tid >> 6, l = tid & 63;
  const int wb = blockIdx.x * 32 + w * 8;          // this wave's 8 rows
  const int seg = l & 15, base = seg * 8, sub = l >> 4;

  const float4* q1 = reinterpret_cast<const float4*>(y1 + (size_t)wb * 128) + 2 * l;
  const float4* q2 = reinterpret_cast<const float4*>(y2 + (size_t)wb * 128) + 2 * l;
  // all 8 vector loads issued before any compute
  float4 a00 = q1[0],   a01 = q1[1];
  float4 a10 = q1[128], a11 = q1[129];
  float4 b00 = q2[0],   b01 = q2[1];
  float4 b10 = q2[128], b11 = q2[129];
  int r0 = wb + sub, r1 = wb + 4 + sub;
  int t0 = tgt[r0], t1 = tgt[r1];

  __shared__ float skl[32], stt[32];
  float av0[8] = {a00.x,a00.y,a00.z,a00.w,a01.x,a01.y,a01.z,a01.w};
  float bv0[8] = {b00.x,b00.y,b00.z,b00.w,b01.x,b01.y,b01.z,b01.w};
  float av1[8] = {a10.x,a10.y,a10.z,a10.w,a11.x,a11.y,a11.z,a11.w};
  float bv1[8] = {b10.x,b10.y,b10.z,b10.w,b11.x,b11.y,b11.z,b11.w};
  process_group(av0, bv0, t0, r0, seg, base, y1, y2, tl, corr, mask, skl, stt, w * 8 + sub);
  process_group(av1, bv1, t1, r1, seg, base, y1, y2, tl, corr, mask, skl, stt, w * 8 + 4 + sub);
  __syncthreads();
  if (tid == 0) {
    double sk = 0.0, st = 0.0;
#pragma unroll
    for (int i = 0; i < 32; i++) { sk += (double)skl[i]; st += (double)stt[i]; }
    int slot = blockIdx.x & (NPART - 1);
    atomicAdd(&acc->kl_part[slot], sk);
    atomicAdd(&acc->tls_part[slot], st);
  }
}

// ============ K2: level-1 histogram (top 12 bits), LDS-privatized, uint4 reads ============
__global__ __launch_bounds__(1024) void k_hist1(const float* __restrict__ tl,
                                                uint* __restrict__ hist1) {
  __shared__ uint h[H1BINS];
  int tid = threadIdx.x;
  for (int j = tid; j < H1BINS; j += 1024) h[j] = 0;
  __syncthreads();
  int i = (blockIdx.x * 1024 + tid) * 4;
  uint4 kk = *reinterpret_cast<const uint4*>(reinterpret_cast<const uint*>(tl) + i);
  atomicAdd(&h[kk.x >> 20], 1u);
  atomicAdd(&h[kk.y >> 20], 1u);
  atomicAdd(&h[kk.z >> 20], 1u);
  atomicAdd(&h[kk.w >> 20], 1u);
  __syncthreads();
  for (int j = tid; j < H1BINS; j += 1024) {
    uint v = h[j];
    if (v) atomicAdd(&hist1[j], v);
  }
}

// ============ K3: level-2 histogram (bits 19:8) gated on B1 ============
__global__ __launch_bounds__(256) void k_hist2(const float* __restrict__ tl,
                                               const uint* __restrict__ hist1,
                                               uint* __restrict__ hist2,
                                               const int* __restrict__ ep) {
  __shared__ uint wsum[4], binrem[2];
  uint B1, r1;
  hist_select(hist1, H1BINS, calc_nr(ep[0]), wsum, binrem, &B1, &r1);
  int i = (blockIdx.x * 256 + threadIdx.x) * 4;
  uint4 kk = *reinterpret_cast<const uint4*>(reinterpret_cast<const uint*>(tl) + i);
  if ((kk.x >> 20) == B1) atomicAdd(&hist2[(kk.x >> 8) & 0xFFFu], 1u);
  if ((kk.y >> 20) == B1) atomicAdd(&hist2[(kk.y >> 8) & 0xFFFu], 1u);
  if ((kk.z >> 20) == B1) atomicAdd(&hist2[(kk.z >> 8) & 0xFFFu], 1u);
  if ((kk.w >> 20) == B1) atomicAdd(&hist2[(kk.w >> 8) & 0xFFFu], 1u);
}

// ============ K4: level-3 histogram (bits 7:0) gated on B1,B2 ============
__global__ __launch_bounds__(256) void k_hist3(const float* __restrict__ tl,
                                               const uint* __restrict__ hist1,
                                               const uint* __restrict__ hist2,
                                               uint* __restrict__ hist3,
                                               const int* __restrict__ ep) {
  __shared__ uint wsum[4], binrem[2];
  uint B1, r1, B2, r2;
  hist_select(hist1, H1BINS, calc_nr(ep[0]), wsum, binrem, &B1, &r1);
  hist_select(hist2, H2BINS, r1, wsum, binrem, &B2, &r2);
  uint pref = (B1 << 12) | B2;
  int i = (blockIdx.x * 256 + threadIdx.x) * 4;
  uint4 kk = *reinterpret_cast<const uint4*>(reinterpret_cast<const uint*>(tl) + i);
  if ((kk.x >> 8) == pref) atomicAdd(&hist3[kk.x & 0xFFu], 1u);
  if ((kk.y >> 8) == pref) atomicAdd(&hist3[kk.y & 0xFFu], 1u);
  if ((kk.z >> 8) == pref) atomicAdd(&hist3[kk.z & 0xFFu], 1u);
  if ((kk.w >> 8) == pref) atomicAdd(&hist3[kk.w & 0xFFu], 1u);
}

// ============ K5: partition by threshold key T, 4 rows/thread ============
__global__ __launch_bounds__(256) void k_partition(const float* __restrict__ tl,
                                                   const float* __restrict__ corr,
                                                   const unsigned char* __restrict__ mask,
                                                   const uint* __restrict__ hist1,
                                                   const uint* __restrict__ hist2,
                                                   const uint* __restrict__ hist3,
                                                   const int* __restrict__ ep,
                                                   Accum* __restrict__ acc) {
  __shared__ uint wsum[4], binrem[2];
  __shared__ double sred[4];
  uint B1, r1, B2, r2, B3, r3;
  hist_select(hist1, H1BINS, calc_nr(ep[0]), wsum, binrem, &B1, &r1);
  hist_select(hist2, H2BINS, r1, wsum, binrem, &B2, &r2);
  hist_select(hist3, H3BINS, r2, wsum, binrem, &B3, &r3);
  uint T = (B1 << 20) | (B2 << 8) | B3;

  int idx = blockIdx.x * 256 + threadIdx.x;
  int i = idx * 4;
  float4 tv = *reinterpret_cast<const float4*>(tl + i);
  float4 cv = *reinterpret_cast<const float4*>(corr + i);
  uint mb = reinterpret_cast<const uint*>(mask)[idx];
  float tvs[4] = {tv.x, tv.y, tv.z, tv.w};
  float cvs[4] = {cv.x, cv.y, cv.z, cv.w};
  double cl = 0.0, co = 0.0, cn = 0.0;
#pragma unroll
  for (int j = 0; j < 4; j++) {
    uint key = __float_as_uint(tvs[j]);
    if (key < T) {
      cl += (double)tvs[j];
    } else if (key == T) {
      uint p = atomicAdd(&acc->tie_cnt, 1u);
      if (p < MAXTIES) acc->tie_idx[p] = (uint)(i + j);
    } else if ((mb >> (8 * j)) & 0xFFu) {
      co += (double)cvs[j]; cn += 1.0;
    }
  }
  double scl = block_sum_d(cl, sred);
  double sco = block_sum_d(co, sred);
  double scn = block_sum_d(cn, sred);
  if (threadIdx.x == 0) {
    acc->clean_part[blockIdx.x] = scl;
    acc->corr_part[blockIdx.x]  = sco;
    acc->cnt_part[blockIdx.x]   = scn;
  }
}

// ============ K6: finalize ============
__global__ __launch_bounds__(256) void k_final(const float* __restrict__ corr,
                                               const unsigned char* __restrict__ mask,
                                               const uint* __restrict__ hist1,
                                               const uint* __restrict__ hist2,
                                               const uint* __restrict__ hist3,
                                               Accum* __restrict__ acc,
                                               const int* __restrict__ ep,
                                               float* __restrict__ out) {
  __shared__ uint wsum[4], binrem[2];
  __shared__ double sred[4];
  int t = threadIdx.x;
  uint nr = calc_nr(ep[0]);
  uint B1, r1, B2, r2, B3, needed;
  hist_select(hist1, H1BINS, nr, wsum, binrem, &B1, &r1);
  hist_select(hist2, H2BINS, r1, wsum, binrem, &B2, &r2);
  hist_select(hist3, H3BINS, r2, wsum, binrem, &B3, &needed);
  uint T = (B1 << 20) | (B2 << 8) | B3;

  double kl = 0, tls = 0, cl = 0, co = 0, cn = 0;
  for (int i = t; i < NPART; i += 256) {
    kl  += acc->kl_part[i];
    tls += acc->tls_part[i];
    cl  += acc->clean_part[i];
    co  += acc->corr_part[i];
    cn  += acc->cnt_part[i];
  }
  kl  = block_sum_d(kl,  sred);
  tls = block_sum_d(tls, sred);
  cl  = block_sum_d(cl,  sred);
  co  = block_sum_d(co,  sred);
  cn  = block_sum_d(cn,  sred);

  if (t == 0) {
    int e = ep[0];
    if (e == 0) { out[0] = (float)(tls / (double)NROWS); return; }

    uint m = acc->tie_cnt; if (m > MAXTIES) m = MAXTIES;
    float Tval = __uint_as_float(T);
    cl += (double)Tval * (double)needed;     // ties going clean (identical value)
    if (m > needed) {
      // stable argsort tie-break by row index
      for (int a2 = 1; a2 < (int)m; a2++) {
        uint v = acc->tie_idx[a2];
        int b2 = a2 - 1;
        while (b2 >= 0 && acc->tie_idx[b2] > v) { acc->tie_idx[b2 + 1] = acc->tie_idx[b2]; b2--; }
        acc->tie_idx[b2 + 1] = v;
      }
      for (uint j = needed; j < m; j++) {
        uint idx = acc->tie_idx[j];
        if (mask[idx]) { co += (double)corr[idx]; cn += 1.0; }
      }
    }
    double clean_loss = cl / (double)nr;
    double corr_mean = (cn > 0.5) ? (co / cn) : 0.0;
    double kl_mean = kl / (double)NROWS;
    out[0] = (float)(clean_loss + corr_mean + 0.1 * kl_mean);
  }
}

extern "C" void kernel_launch(void* const* d_in, const int* in_sizes, int n_in,
                              void* d_out, int out_size, void* d_ws, size_t ws_size,
                              hipStream_t stream) {
  const float* y1 = (const float*)d_in[0];
  const float* y2 = (const float*)d_in[1];
  const int* tgt = (const int*)d_in[2];
  const int* epoch = (const int*)d_in[3];
  float* out = (float*)d_out;

  float* tl = (float*)d_ws;                                   // N floats
  float* corrv = tl + NROWS;                                  // N floats
  unsigned char* mask = (unsigned char*)(corrv + NROWS);      // N bytes
  uint* hist1 = (uint*)(mask + NROWS);                        // 4096
  uint* hist2 = hist1 + H1BINS;                               // 4096
  uint* hist3 = hist2 + H2BINS;                               // 256
  Accum* acc = (Accum*)(hist3 + H3BINS);

  size_t zbytes = (size_t)(H1BINS + H2BINS + H3BINS) * 4 + sizeof(Accum);
  hipMemsetAsync(hist1, 0, zbytes, stream);

  k_rows<<<NROWS / 32, 256, 0, stream>>>(y1, y2, tgt, tl, corrv, mask, acc);
  k_hist1<<<NROWS / 4096, 1024, 0, stream>>>(tl, hist1);
  k_hist2<<<NROWS / 1024, 256, 0, stream>>>(tl, hist1, hist2, epoch);
  k_hist3<<<NROWS / 1024, 256, 0, stream>>>(tl, hist1, hist2, hist3, epoch);
  k_partition<<<NROWS / 1024, 256, 0, stream>>>(tl, corrv, mask, hist1, hist2, hist3, epoch, acc);
  k_final<<<1, 256, 0, stream>>>(corrv, mask, hist1, hist2, hist3, acc, epoch, out);
}